// Round 2
// baseline (385.777 us; speedup 1.0000x reference)
//
#include <hip/hip_runtime.h>

// SSIM3D, (4,1,128,128,128) fp32, separable 11-tap Gaussian, scalar mean out.
//
// R8 == R7 resubmit (R7 bench was an infra failure: container died before
// running; code audit found no OOB / misalignment / deadlock mechanism).
//
// R7: ssimA rebuilt around a per-wave PRIVATE LDS row ring.
//   - R6 post-mortem: depth-2 register pipeline (84 VGPRs of staged data) vs
//     128-VGPR cap => compiler sank the "prefetch" loads to their use; 70%
//     stall, VALUBusy 29%. Fix: staged data lives in LDS (4-slot ring), the
//     in-flight state is 3 float4 (12 VGPRs). Barrier-free: each wave owns
//     its ring (within-wave lgkmcnt ordering only, no syncthreads drain).
//   - 1 float4 global load/thread/step (lanes 0-31 img1 row, 32-63 img2 row)
//     instead of 14 overlapping float2 (8x fewer requested bytes).
//   - Rows zero-padded in LDS => exact 11-tap conv, no w14/cc masks.
//   - Three-phase loop (head/steady/drain): steady 22 steps are branch-free,
//     all bound checks compile away.
//   - Gaussian weights readfirstlane'd to SGPRs (frees VGPRs, scalar FMA op).
// ssimB: prefetch depth 2->4 (fits: 20 regs) + same 3-phase split + SGPR g.

#define SLICE (128*128)        // 16384
#define S  (128*SLICE)         // 2097152 per field per batch
#define C1_ 0.0001f
#define C2_ 0.0009f

__device__ __forceinline__ void make_g_s(float* gs) {
    float g[11]; float s = 0.f;
#pragma unroll
    for (int i = 0; i < 11; ++i) {
        float d = (float)(i - 5);
        g[i] = __expf(-d * d / 4.5f);
        s += g[i];
    }
    float inv = 1.f / s;
#pragma unroll
    for (int i = 0; i < 11; ++i)
        gs[i] = __int_as_float(__builtin_amdgcn_readfirstlane(
                    __float_as_int(g[i] * inv)));
}

// ---------------- Kernel A: x-conv + y-conv, walk y ----------------
// grid: 4n * 128z * 4yc = 2048 blocks of 128 threads (2 independent waves).
// Thread owns x = tid; walks 32 y outputs (42 input rows).
// Per-wave LDS ring: 4 slots x (img1 row | img2 row), each row padded to 160
// floats (data at dwords [8..135], zeros outside) so taps x-5..x+5 never
// need a bounds check.
#define RB    160              // dwords per padded row
#define RSLOT (2*RB)           // 320 dwords per ring slot
#define WRING (4*RSLOT)        // 1280 dwords per wave ring

// One pipeline step. T_ runtime step index, TM_ compile-time (== T_ mod 11),
// J0_/J1_ compile-time y-tap range, RPE_/WPE_ read/write slot pointers.
#define STEPA(T_, TM_, J0_, J1_, STORE_, OKC_, RPE_, WPE_) do {               \
    const int T__ = (T_);                                                     \
    int sp__ = T__ + 3; if (sp__ > 41) sp__ = 41;                             \
    int rowc__ = min(max(y0 + sp__ - 5, 0), 127);                             \
    float4 Rn__ = *(const float4*)(src + (size_t)rowc__ * 128);               \
    if (OKC_) {                                                               \
        const float* rp__ = (RPE_);                                           \
        float v1__[12], v2__[12];                                             \
        _Pragma("unroll")                                                     \
        for (int j = 0; j < 12; ++j) {                                        \
            v1__[j] = rp__[j]; v2__[j] = rp__[RB + j];                        \
        }                                                                     \
        float u1__ = 0.f, u2__ = 0.f, a11__ = 0.f, a22__ = 0.f, a12__ = 0.f;  \
        _Pragma("unroll")                                                     \
        for (int j = 0; j < 11; ++j) {                                        \
            float wj__ = gs[j];                                               \
            float av__ = v1__[j], bv__ = v2__[j];                             \
            float ta__ = wj__ * av__, tb__ = wj__ * bv__;                     \
            u1__ += ta__; u2__ += tb__;                                       \
            a11__ = fmaf(ta__, av__, a11__);                                  \
            a12__ = fmaf(ta__, bv__, a12__);                                  \
            a22__ = fmaf(tb__, bv__, a22__);                                  \
        }                                                                     \
        _Pragma("unroll")                                                     \
        for (int j = (J0_); j <= (J1_); ++j) {                                \
            const int sl__ = ((TM_) + j + 1) % 11;                            \
            float wy__ = gs[10 - j];                                          \
            acc[0][sl__] = fmaf(wy__, u1__,  acc[0][sl__]);                   \
            acc[1][sl__] = fmaf(wy__, u2__,  acc[1][sl__]);                   \
            acc[2][sl__] = fmaf(wy__, a11__, acc[2][sl__]);                   \
            acc[3][sl__] = fmaf(wy__, a22__, acc[3][sl__]);                   \
            acc[4][sl__] = fmaf(wy__, a12__, acc[4][sl__]);                   \
        }                                                                     \
    }                                                                         \
    *(float4*)(WPE_) = h1;          /* stage row T+1 (loaded 3 steps ago) */  \
    if (STORE_) {                                                             \
        const int es__ = ((TM_) + 1) % 11;                                    \
        size_t wo__ = (size_t)(y0 + T__ - 10) * 128;                          \
        _Pragma("unroll")                                                     \
        for (int f = 0; f < 5; ++f) {                                         \
            fb[(size_t)f * S + wo__] = acc[f][es__];                          \
            acc[f][es__] = 0.f;                                               \
        }                                                                     \
    }                                                                         \
    h1 = h2; h2 = Rn__;                                                       \
} while (0)

__global__ __launch_bounds__(128, 4)
void ssimA(const float* __restrict__ img1, const float* __restrict__ img2,
           float* __restrict__ fields) {
    __shared__ __align__(16) float ring[2 * WRING];   // 10 KiB
    float gs[11]; make_g_s(gs);
    const int x = threadIdx.x;                 // 0..127 (output column)
    const int w = x >> 6, l = x & 63;          // wave, lane
    const int b = blockIdx.x;
    const int yc = b & 3, z = (b >> 2) & 127, n = b >> 9;
    const int y0 = yc * 32;
    // lanes 0-31 stage the img1 row (float4 each), lanes 32-63 the img2 row
    const float* src = (l < 32 ? img1 : img2)
                     + (size_t)n * S + (size_t)z * SLICE + 4 * (l & 31);
    float* fb = fields + (size_t)n * 5 * S + (size_t)z * SLICE + x;

    float* wring = ring + w * WRING;           // private per-wave ring
    float* p_rd = wring + (x + 3);             // == [8 + x-5]; +j / +RB+j taps
    float* p_wr = wring + ((l < 32) ? 0 : RB) + 8 + 4 * (l & 31);

    // zero whole ring once: pads stay zero forever (x-boundary = free)
    for (int i = l; i < WRING; i += 64) wring[i] = 0.f;

    float acc[5][11];
#pragma unroll
    for (int f = 0; f < 5; ++f)
#pragma unroll
        for (int s2 = 0; s2 < 11; ++s2) acc[f][s2] = 0.f;

    // prologue: rows for steps 0,1,2; slot0 written, rows 1,2 held in regs
    float4 h1, h2;
    {
        int r0 = min(max(y0 - 5, 0), 127);
        int r1 = min(max(y0 - 4, 0), 127);
        int r2 = min(max(y0 - 3, 0), 127);
        float4 R0 = *(const float4*)(src + (size_t)r0 * 128);
        h1        = *(const float4*)(src + (size_t)r1 * 128);
        h2        = *(const float4*)(src + (size_t)r2 * 128);
        *(float4*)(p_wr) = R0;                 // slot 0
    }

    // head: t = 0..9 (partial y-window, row may be < 0; no stores)
#pragma unroll
    for (int t = 0; t < 10; ++t) {
        STEPA(t, t, 10 - t, 10, false, (y0 + t - 5 >= 0),
              p_rd + (t & 3) * RSLOT, p_wr + ((t + 1) & 3) * RSLOT);
    }
    // steady: t = 10..31 -- branch-free, full window, store every step
    {
        int ro = 2 * RSLOT, wro = 3 * RSLOT;   // slot(10), slot(11)
#pragma unroll 1
        for (int blk = 0; blk < 2; ++blk) {
#pragma unroll
            for (int tt = 0; tt < 11; ++tt) {
                STEPA(10 + blk * 11 + tt, 10 + tt, 0, 10, true, true,
                      p_rd + ro, p_wr + wro);
                ro = wro;
                wro += RSLOT; if (wro == WRING) wro = 0;
            }
        }
    }
    // drain: t = 32..41 (partial y-window, row may be > 127; store always)
#pragma unroll
    for (int t = 32; t < 42; ++t) {
        STEPA(t, t % 11, 0, 41 - t, true, (y0 + t - 5 < 128),
              p_rd + (t & 3) * RSLOT, p_wr + ((t + 1) & 3) * RSLOT);
    }
}

// ---------------- Kernel B: z-conv + map + reduce, walk z ----------------
// grid: 4n * 64y2 * 4zc = 1024 blocks of 256 threads (4 waves).
// Thread owns (x = tid&127, y = 2*y2 + (tid>>7)); walks 32 z outputs.
// Batches reversed (freshest A output first -> L3 hits). Depth-4 prefetch
// (5 floats/step pipeline stage = cheap in regs), 3-phase branch-free loop.
#define STEPB(T_, TM_, J0_, J1_, STORE_, OKC_) do {                           \
    const int T__ = (T_);                                                     \
    int sp__ = T__ + 4; if (sp__ > 41) sp__ = 41;                             \
    size_t off__ = (size_t)min(max(z0 + sp__ - 5, 0), 127) * SLICE;           \
    float N__[5];                                                             \
    _Pragma("unroll")                                                         \
    for (int f = 0; f < 5; ++f) N__[f] = base[(size_t)f * S + off__];         \
    if (OKC_) {                                                               \
        _Pragma("unroll")                                                     \
        for (int j = (J0_); j <= (J1_); ++j) {                                \
            const int sl__ = ((TM_) + j + 1) % 11;                            \
            float wz__ = gs[10 - j];                                          \
            acc[0][sl__] = fmaf(wz__, P0[0], acc[0][sl__]);                   \
            acc[1][sl__] = fmaf(wz__, P0[1], acc[1][sl__]);                   \
            acc[2][sl__] = fmaf(wz__, P0[2], acc[2][sl__]);                   \
            acc[3][sl__] = fmaf(wz__, P0[3], acc[3][sl__]);                   \
            acc[4][sl__] = fmaf(wz__, P0[4], acc[4][sl__]);                   \
        }                                                                     \
    }                                                                         \
    if (STORE_) {                                                             \
        const int es__ = ((TM_) + 1) % 11;                                    \
        float m1__ = acc[0][es__], m2__ = acc[1][es__];                       \
        float p11__ = acc[2][es__], p22__ = acc[3][es__], p12__ = acc[4][es__];\
        float m1s__ = m1__ * m1__, m2s__ = m2__ * m2__, m12__ = m1__ * m2__;  \
        float v1c__ = p11__ - m1s__, v2c__ = p22__ - m2s__, cv__ = p12__ - m12__;\
        float num__ = (2.f * m12__ + C1_) * (2.f * cv__ + C2_);               \
        float den__ = (m1s__ + m2s__ + C1_) * (v1c__ + v2c__ + C2_);          \
        sum += num__ / den__;                                                 \
        _Pragma("unroll")                                                     \
        for (int f = 0; f < 5; ++f) acc[f][es__] = 0.f;                       \
    }                                                                         \
    _Pragma("unroll")                                                         \
    for (int f = 0; f < 5; ++f) {                                             \
        P0[f] = P1[f]; P1[f] = P2[f]; P2[f] = P3[f]; P3[f] = N__[f];          \
    }                                                                         \
} while (0)

__global__ __launch_bounds__(256, 4)
void ssimB(const float* __restrict__ fields, float* __restrict__ partials) {
    float gs[11]; make_g_s(gs);
    const int tid = threadIdx.x;
    const int x = tid & 127, yr = tid >> 7;
    const int b = blockIdx.x;
    const int zc = b & 3, y2 = (b >> 2) & 63;
    const int n = 3 - (b >> 8);                 // reverse batches (L3 hits)
    const int y = y2 * 2 + yr;
    const int z0 = zc * 32;
    const float* base = fields + (size_t)n * 5 * S + (size_t)y * 128 + x;

    float acc[5][11];
#pragma unroll
    for (int f = 0; f < 5; ++f)
#pragma unroll
        for (int s2 = 0; s2 < 11; ++s2) acc[f][s2] = 0.f;

    float sum = 0.f;

    // depth-4 prologue: slices for steps 0..3
    float P0[5], P1[5], P2[5], P3[5];
    {
        size_t o0 = (size_t)min(max(z0 - 5, 0), 127) * SLICE;
        size_t o1 = (size_t)min(max(z0 - 4, 0), 127) * SLICE;
        size_t o2 = (size_t)min(max(z0 - 3, 0), 127) * SLICE;
        size_t o3 = (size_t)min(max(z0 - 2, 0), 127) * SLICE;
#pragma unroll
        for (int f = 0; f < 5; ++f) {
            P0[f] = base[(size_t)f * S + o0];
            P1[f] = base[(size_t)f * S + o1];
            P2[f] = base[(size_t)f * S + o2];
            P3[f] = base[(size_t)f * S + o3];
        }
    }

    // head: t = 0..9
#pragma unroll
    for (int t = 0; t < 10; ++t) {
        STEPB(t, t, 10 - t, 10, false, (z0 + t - 5 >= 0));
    }
    // steady: t = 10..31 -- branch-free
#pragma unroll 1
    for (int blk = 0; blk < 2; ++blk) {
#pragma unroll
        for (int tt = 0; tt < 11; ++tt) {
            STEPB(10 + blk * 11 + tt, 10 + tt, 0, 10, true, true);
        }
    }
    // drain: t = 32..41
#pragma unroll
    for (int t = 32; t < 42; ++t) {
        STEPB(t, t % 11, 0, 41 - t, true, (z0 + t - 5 < 128));
    }

    // 4-wave reduce
#pragma unroll
    for (int o = 32; o > 0; o >>= 1) sum += __shfl_down(sum, o, 64);
    __shared__ float ws4[4];
    if ((tid & 63) == 0) ws4[tid >> 6] = sum;
    __syncthreads();
    if (tid == 0) partials[blockIdx.x] = ws4[0] + ws4[1] + ws4[2] + ws4[3];
}

// ---------------- final reduce ----------------
__global__ void ssim_final(const float* __restrict__ partial, int n,
                           float* __restrict__ out, double inv_count) {
    int tid = threadIdx.x;
    double s = 0.0;
    for (int i = tid; i < n; i += 256) s += (double)partial[i];
#pragma unroll
    for (int o = 32; o > 0; o >>= 1) s += __shfl_down(s, o, 64);
    __shared__ double wsum[4];
    int lane = tid & 63, wid = tid >> 6;
    if (lane == 0) wsum[wid] = s;
    __syncthreads();
    if (tid == 0)
        out[0] = (float)((wsum[0] + wsum[1] + wsum[2] + wsum[3]) * inv_count);
}

extern "C" void kernel_launch(void* const* d_in, const int* in_sizes, int n_in,
                              void* d_out, int out_size, void* d_ws, size_t ws_size,
                              hipStream_t stream) {
    const float* img1 = (const float*)d_in[0];
    const float* img2 = (const float*)d_in[1];
    float* out = (float*)d_out;

    float* fields   = (float*)d_ws;                    // 20*S floats (167.8 MB)
    float* partials = fields + 20 * (size_t)S;         // 1024 floats

    ssimA<<<2048, 128, 0, stream>>>(img1, img2, fields);
    ssimB<<<1024, 256, 0, stream>>>(fields, partials);
    ssim_final<<<1, 256, 0, stream>>>(partials, 1024, out,
                                      1.0 / ((double)S * 4));
}

// Round 3
// 264.318 us; speedup vs baseline: 1.4595x; 1.4595x over previous
//
#include <hip/hip_runtime.h>

// SSIM3D, (4,1,128,128,128) fp32, separable 11-tap Gaussian, scalar mean out.
//
// R9 = R8 with ONLY the launch bounds relaxed (one-variable experiment).
// R8 post-mortem: PASSED (absmax 0) -> LDS-ring pipeline is exact. But
// WRITE_SIZE 380MB vs logical 168MB + FETCH 202MB vs ~64MB + VGPR_Count=64
// == scratch spills: minWavesPerEU=4 capped VGPRs at 128 and the allocator
// spilled the ~110-reg live state (acc[5][11] etc) to scratch each step.
// Fix: minEU 4->3 (cap ~168, demand ~110, 12 waves/CU retained).
// Invariant check next profile: ssimA WRITE_SIZE == 167936 KB exactly.
//
// R7/R8 design (kept verbatim):
//   - ssimA: per-wave PRIVATE LDS row ring (4 slots), barrier-free; 1 float4
//     global load/thread/step; zero-padded rows => exact 11-tap, maskless;
//     3-phase loop (head/steady/drain), steady 22 steps branch-free;
//     Gaussian weights readfirstlane'd to SGPRs.
//   - ssimB: depth-4 register prefetch + same 3-phase split + SGPR weights;
//     batches reversed so A's freshest output is L3-resident.

#define SLICE (128*128)        // 16384
#define S  (128*SLICE)         // 2097152 per field per batch
#define C1_ 0.0001f
#define C2_ 0.0009f

__device__ __forceinline__ void make_g_s(float* gs) {
    float g[11]; float s = 0.f;
#pragma unroll
    for (int i = 0; i < 11; ++i) {
        float d = (float)(i - 5);
        g[i] = __expf(-d * d / 4.5f);
        s += g[i];
    }
    float inv = 1.f / s;
#pragma unroll
    for (int i = 0; i < 11; ++i)
        gs[i] = __int_as_float(__builtin_amdgcn_readfirstlane(
                    __float_as_int(g[i] * inv)));
}

// ---------------- Kernel A: x-conv + y-conv, walk y ----------------
// grid: 4n * 128z * 4yc = 2048 blocks of 128 threads (2 independent waves).
// Thread owns x = tid; walks 32 y outputs (42 input rows).
// Per-wave LDS ring: 4 slots x (img1 row | img2 row), each row padded to 160
// floats (data at dwords [8..135], zeros outside) so taps x-5..x+5 never
// need a bounds check.
#define RB    160              // dwords per padded row
#define RSLOT (2*RB)           // 320 dwords per ring slot
#define WRING (4*RSLOT)        // 1280 dwords per wave ring

// One pipeline step. T_ runtime step index, TM_ compile-time (== T_ mod 11),
// J0_/J1_ compile-time y-tap range, RPE_/WPE_ read/write slot pointers.
#define STEPA(T_, TM_, J0_, J1_, STORE_, OKC_, RPE_, WPE_) do {               \
    const int T__ = (T_);                                                     \
    int sp__ = T__ + 3; if (sp__ > 41) sp__ = 41;                             \
    int rowc__ = min(max(y0 + sp__ - 5, 0), 127);                             \
    float4 Rn__ = *(const float4*)(src + (size_t)rowc__ * 128);               \
    if (OKC_) {                                                               \
        const float* rp__ = (RPE_);                                           \
        float v1__[12], v2__[12];                                             \
        _Pragma("unroll")                                                     \
        for (int j = 0; j < 12; ++j) {                                        \
            v1__[j] = rp__[j]; v2__[j] = rp__[RB + j];                        \
        }                                                                     \
        float u1__ = 0.f, u2__ = 0.f, a11__ = 0.f, a22__ = 0.f, a12__ = 0.f;  \
        _Pragma("unroll")                                                     \
        for (int j = 0; j < 11; ++j) {                                        \
            float wj__ = gs[j];                                               \
            float av__ = v1__[j], bv__ = v2__[j];                             \
            float ta__ = wj__ * av__, tb__ = wj__ * bv__;                     \
            u1__ += ta__; u2__ += tb__;                                       \
            a11__ = fmaf(ta__, av__, a11__);                                  \
            a12__ = fmaf(ta__, bv__, a12__);                                  \
            a22__ = fmaf(tb__, bv__, a22__);                                  \
        }                                                                     \
        _Pragma("unroll")                                                     \
        for (int j = (J0_); j <= (J1_); ++j) {                                \
            const int sl__ = ((TM_) + j + 1) % 11;                            \
            float wy__ = gs[10 - j];                                          \
            acc[0][sl__] = fmaf(wy__, u1__,  acc[0][sl__]);                   \
            acc[1][sl__] = fmaf(wy__, u2__,  acc[1][sl__]);                   \
            acc[2][sl__] = fmaf(wy__, a11__, acc[2][sl__]);                   \
            acc[3][sl__] = fmaf(wy__, a22__, acc[3][sl__]);                   \
            acc[4][sl__] = fmaf(wy__, a12__, acc[4][sl__]);                   \
        }                                                                     \
    }                                                                         \
    *(float4*)(WPE_) = h1;          /* stage row T+1 (loaded 3 steps ago) */  \
    if (STORE_) {                                                             \
        const int es__ = ((TM_) + 1) % 11;                                    \
        size_t wo__ = (size_t)(y0 + T__ - 10) * 128;                          \
        _Pragma("unroll")                                                     \
        for (int f = 0; f < 5; ++f) {                                         \
            fb[(size_t)f * S + wo__] = acc[f][es__];                          \
            acc[f][es__] = 0.f;                                               \
        }                                                                     \
    }                                                                         \
    h1 = h2; h2 = Rn__;                                                       \
} while (0)

__global__ __launch_bounds__(128, 3)
void ssimA(const float* __restrict__ img1, const float* __restrict__ img2,
           float* __restrict__ fields) {
    __shared__ __align__(16) float ring[2 * WRING];   // 10 KiB
    float gs[11]; make_g_s(gs);
    const int x = threadIdx.x;                 // 0..127 (output column)
    const int w = x >> 6, l = x & 63;          // wave, lane
    const int b = blockIdx.x;
    const int yc = b & 3, z = (b >> 2) & 127, n = b >> 9;
    const int y0 = yc * 32;
    // lanes 0-31 stage the img1 row (float4 each), lanes 32-63 the img2 row
    const float* src = (l < 32 ? img1 : img2)
                     + (size_t)n * S + (size_t)z * SLICE + 4 * (l & 31);
    float* fb = fields + (size_t)n * 5 * S + (size_t)z * SLICE + x;

    float* wring = ring + w * WRING;           // private per-wave ring
    float* p_rd = wring + (x + 3);             // == [8 + x-5]; +j / +RB+j taps
    float* p_wr = wring + ((l < 32) ? 0 : RB) + 8 + 4 * (l & 31);

    // zero whole ring once: pads stay zero forever (x-boundary = free)
    for (int i = l; i < WRING; i += 64) wring[i] = 0.f;

    float acc[5][11];
#pragma unroll
    for (int f = 0; f < 5; ++f)
#pragma unroll
        for (int s2 = 0; s2 < 11; ++s2) acc[f][s2] = 0.f;

    // prologue: rows for steps 0,1,2; slot0 written, rows 1,2 held in regs
    float4 h1, h2;
    {
        int r0 = min(max(y0 - 5, 0), 127);
        int r1 = min(max(y0 - 4, 0), 127);
        int r2 = min(max(y0 - 3, 0), 127);
        float4 R0 = *(const float4*)(src + (size_t)r0 * 128);
        h1        = *(const float4*)(src + (size_t)r1 * 128);
        h2        = *(const float4*)(src + (size_t)r2 * 128);
        *(float4*)(p_wr) = R0;                 // slot 0
    }

    // head: t = 0..9 (partial y-window, row may be < 0; no stores)
#pragma unroll
    for (int t = 0; t < 10; ++t) {
        STEPA(t, t, 10 - t, 10, false, (y0 + t - 5 >= 0),
              p_rd + (t & 3) * RSLOT, p_wr + ((t + 1) & 3) * RSLOT);
    }
    // steady: t = 10..31 -- branch-free, full window, store every step
    {
        int ro = 2 * RSLOT, wro = 3 * RSLOT;   // slot(10), slot(11)
#pragma unroll 1
        for (int blk = 0; blk < 2; ++blk) {
#pragma unroll
            for (int tt = 0; tt < 11; ++tt) {
                STEPA(10 + blk * 11 + tt, 10 + tt, 0, 10, true, true,
                      p_rd + ro, p_wr + wro);
                ro = wro;
                wro += RSLOT; if (wro == WRING) wro = 0;
            }
        }
    }
    // drain: t = 32..41 (partial y-window, row may be > 127; store always)
#pragma unroll
    for (int t = 32; t < 42; ++t) {
        STEPA(t, t % 11, 0, 41 - t, true, (y0 + t - 5 < 128),
              p_rd + (t & 3) * RSLOT, p_wr + ((t + 1) & 3) * RSLOT);
    }
}

// ---------------- Kernel B: z-conv + map + reduce, walk z ----------------
// grid: 4n * 64y2 * 4zc = 1024 blocks of 256 threads (4 waves).
// Thread owns (x = tid&127, y = 2*y2 + (tid>>7)); walks 32 z outputs.
// Batches reversed (freshest A output first -> L3 hits). Depth-4 prefetch
// (5 floats/step pipeline stage = cheap in regs), 3-phase branch-free loop.
#define STEPB(T_, TM_, J0_, J1_, STORE_, OKC_) do {                           \
    const int T__ = (T_);                                                     \
    int sp__ = T__ + 4; if (sp__ > 41) sp__ = 41;                             \
    size_t off__ = (size_t)min(max(z0 + sp__ - 5, 0), 127) * SLICE;           \
    float N__[5];                                                             \
    _Pragma("unroll")                                                         \
    for (int f = 0; f < 5; ++f) N__[f] = base[(size_t)f * S + off__];         \
    if (OKC_) {                                                               \
        _Pragma("unroll")                                                     \
        for (int j = (J0_); j <= (J1_); ++j) {                                \
            const int sl__ = ((TM_) + j + 1) % 11;                            \
            float wz__ = gs[10 - j];                                          \
            acc[0][sl__] = fmaf(wz__, P0[0], acc[0][sl__]);                   \
            acc[1][sl__] = fmaf(wz__, P0[1], acc[1][sl__]);                   \
            acc[2][sl__] = fmaf(wz__, P0[2], acc[2][sl__]);                   \
            acc[3][sl__] = fmaf(wz__, P0[3], acc[3][sl__]);                   \
            acc[4][sl__] = fmaf(wz__, P0[4], acc[4][sl__]);                   \
        }                                                                     \
    }                                                                         \
    if (STORE_) {                                                             \
        const int es__ = ((TM_) + 1) % 11;                                    \
        float m1__ = acc[0][es__], m2__ = acc[1][es__];                       \
        float p11__ = acc[2][es__], p22__ = acc[3][es__], p12__ = acc[4][es__];\
        float m1s__ = m1__ * m1__, m2s__ = m2__ * m2__, m12__ = m1__ * m2__;  \
        float v1c__ = p11__ - m1s__, v2c__ = p22__ - m2s__, cv__ = p12__ - m12__;\
        float num__ = (2.f * m12__ + C1_) * (2.f * cv__ + C2_);               \
        float den__ = (m1s__ + m2s__ + C1_) * (v1c__ + v2c__ + C2_);          \
        sum += num__ / den__;                                                 \
        _Pragma("unroll")                                                     \
        for (int f = 0; f < 5; ++f) acc[f][es__] = 0.f;                       \
    }                                                                         \
    _Pragma("unroll")                                                         \
    for (int f = 0; f < 5; ++f) {                                             \
        P0[f] = P1[f]; P1[f] = P2[f]; P2[f] = P3[f]; P3[f] = N__[f];          \
    }                                                                         \
} while (0)

__global__ __launch_bounds__(256, 3)
void ssimB(const float* __restrict__ fields, float* __restrict__ partials) {
    float gs[11]; make_g_s(gs);
    const int tid = threadIdx.x;
    const int x = tid & 127, yr = tid >> 7;
    const int b = blockIdx.x;
    const int zc = b & 3, y2 = (b >> 2) & 63;
    const int n = 3 - (b >> 8);                 // reverse batches (L3 hits)
    const int y = y2 * 2 + yr;
    const int z0 = zc * 32;
    const float* base = fields + (size_t)n * 5 * S + (size_t)y * 128 + x;

    float acc[5][11];
#pragma unroll
    for (int f = 0; f < 5; ++f)
#pragma unroll
        for (int s2 = 0; s2 < 11; ++s2) acc[f][s2] = 0.f;

    float sum = 0.f;

    // depth-4 prologue: slices for steps 0..3
    float P0[5], P1[5], P2[5], P3[5];
    {
        size_t o0 = (size_t)min(max(z0 - 5, 0), 127) * SLICE;
        size_t o1 = (size_t)min(max(z0 - 4, 0), 127) * SLICE;
        size_t o2 = (size_t)min(max(z0 - 3, 0), 127) * SLICE;
        size_t o3 = (size_t)min(max(z0 - 2, 0), 127) * SLICE;
#pragma unroll
        for (int f = 0; f < 5; ++f) {
            P0[f] = base[(size_t)f * S + o0];
            P1[f] = base[(size_t)f * S + o1];
            P2[f] = base[(size_t)f * S + o2];
            P3[f] = base[(size_t)f * S + o3];
        }
    }

    // head: t = 0..9
#pragma unroll
    for (int t = 0; t < 10; ++t) {
        STEPB(t, t, 10 - t, 10, false, (z0 + t - 5 >= 0));
    }
    // steady: t = 10..31 -- branch-free
#pragma unroll 1
    for (int blk = 0; blk < 2; ++blk) {
#pragma unroll
        for (int tt = 0; tt < 11; ++tt) {
            STEPB(10 + blk * 11 + tt, 10 + tt, 0, 10, true, true);
        }
    }
    // drain: t = 32..41
#pragma unroll
    for (int t = 32; t < 42; ++t) {
        STEPB(t, t % 11, 0, 41 - t, true, (z0 + t - 5 < 128));
    }

    // 4-wave reduce
#pragma unroll
    for (int o = 32; o > 0; o >>= 1) sum += __shfl_down(sum, o, 64);
    __shared__ float ws4[4];
    if ((tid & 63) == 0) ws4[tid >> 6] = sum;
    __syncthreads();
    if (tid == 0) partials[blockIdx.x] = ws4[0] + ws4[1] + ws4[2] + ws4[3];
}

// ---------------- final reduce ----------------
__global__ void ssim_final(const float* __restrict__ partial, int n,
                           float* __restrict__ out, double inv_count) {
    int tid = threadIdx.x;
    double s = 0.0;
    for (int i = tid; i < n; i += 256) s += (double)partial[i];
#pragma unroll
    for (int o = 32; o > 0; o >>= 1) s += __shfl_down(s, o, 64);
    __shared__ double wsum[4];
    int lane = tid & 63, wid = tid >> 6;
    if (lane == 0) wsum[wid] = s;
    __syncthreads();
    if (tid == 0)
        out[0] = (float)((wsum[0] + wsum[1] + wsum[2] + wsum[3]) * inv_count);
}

extern "C" void kernel_launch(void* const* d_in, const int* in_sizes, int n_in,
                              void* d_out, int out_size, void* d_ws, size_t ws_size,
                              hipStream_t stream) {
    const float* img1 = (const float*)d_in[0];
    const float* img2 = (const float*)d_in[1];
    float* out = (float*)d_out;

    float* fields   = (float*)d_ws;                    // 20*S floats (167.8 MB)
    float* partials = fields + 20 * (size_t)S;         // 1024 floats

    ssimA<<<2048, 128, 0, stream>>>(img1, img2, fields);
    ssimB<<<1024, 256, 0, stream>>>(fields, partials);
    ssim_final<<<1, 256, 0, stream>>>(partials, 1024, out,
                                      1.0 / ((double)S * 4));
}

// Round 4
// 183.030 us; speedup vs baseline: 2.1077x; 1.4441x over previous
//
#include <hip/hip_runtime.h>

// SSIM3D, (4,1,128,128,128) fp32, separable 11-tap Gaussian, scalar mean out.
//
// R10 = R9 with ONLY launch bounds changed (register-budget fix).
// R9 post-mortem: still spilling (WRITE 241MB vs 168MB logical, VGPR=84).
// VGPR progression (128,2)->128, (128,3)->84=512/6, (128,4)->64=512/8 shows
// the effective per-wave cap is 512/(minEU * waves_per_block) on this
// toolchain -- my "168 cap" was actually ~85, right at the live-state size.
// ssimB at (256,3) had effective cap ~42 vs ~85 live -> B regressed to
// ~130us (total 264 - A 128 - final ~5).
// Fix (no-spill under either interpretation of arg2):
//   ssimA: (128,2)  -- empirically zero-spill at 128 VGPRs in R6
//   ssimB: (256,1)  -- cap >=128 worst-case vs ~85 demand
// Invariant check next profile: ssimA WRITE_SIZE == 167936 KB exactly.
//
// Design (kept verbatim from R8/R9, absmax 0.0 twice):
//   - ssimA: per-wave PRIVATE LDS row ring (4 slots), barrier-free; 1 float4
//     global load/thread/step; zero-padded rows => exact 11-tap, maskless;
//     3-phase loop (head/steady/drain), steady 22 steps branch-free;
//     Gaussian weights readfirstlane'd to SGPRs.
//   - ssimB: depth-4 register prefetch + same 3-phase split + SGPR weights;
//     batches reversed so A's freshest output is L3-resident.

#define SLICE (128*128)        // 16384
#define S  (128*SLICE)         // 2097152 per field per batch
#define C1_ 0.0001f
#define C2_ 0.0009f

__device__ __forceinline__ void make_g_s(float* gs) {
    float g[11]; float s = 0.f;
#pragma unroll
    for (int i = 0; i < 11; ++i) {
        float d = (float)(i - 5);
        g[i] = __expf(-d * d / 4.5f);
        s += g[i];
    }
    float inv = 1.f / s;
#pragma unroll
    for (int i = 0; i < 11; ++i)
        gs[i] = __int_as_float(__builtin_amdgcn_readfirstlane(
                    __float_as_int(g[i] * inv)));
}

// ---------------- Kernel A: x-conv + y-conv, walk y ----------------
// grid: 4n * 128z * 4yc = 2048 blocks of 128 threads (2 independent waves).
// Thread owns x = tid; walks 32 y outputs (42 input rows).
// Per-wave LDS ring: 4 slots x (img1 row | img2 row), each row padded to 160
// floats (data at dwords [8..135], zeros outside) so taps x-5..x+5 never
// need a bounds check.
#define RB    160              // dwords per padded row
#define RSLOT (2*RB)           // 320 dwords per ring slot
#define WRING (4*RSLOT)        // 1280 dwords per wave ring

// One pipeline step. T_ runtime step index, TM_ compile-time (== T_ mod 11),
// J0_/J1_ compile-time y-tap range, RPE_/WPE_ read/write slot pointers.
#define STEPA(T_, TM_, J0_, J1_, STORE_, OKC_, RPE_, WPE_) do {               \
    const int T__ = (T_);                                                     \
    int sp__ = T__ + 3; if (sp__ > 41) sp__ = 41;                             \
    int rowc__ = min(max(y0 + sp__ - 5, 0), 127);                             \
    float4 Rn__ = *(const float4*)(src + (size_t)rowc__ * 128);               \
    if (OKC_) {                                                               \
        const float* rp__ = (RPE_);                                           \
        float v1__[12], v2__[12];                                             \
        _Pragma("unroll")                                                     \
        for (int j = 0; j < 12; ++j) {                                        \
            v1__[j] = rp__[j]; v2__[j] = rp__[RB + j];                        \
        }                                                                     \
        float u1__ = 0.f, u2__ = 0.f, a11__ = 0.f, a22__ = 0.f, a12__ = 0.f;  \
        _Pragma("unroll")                                                     \
        for (int j = 0; j < 11; ++j) {                                        \
            float wj__ = gs[j];                                               \
            float av__ = v1__[j], bv__ = v2__[j];                             \
            float ta__ = wj__ * av__, tb__ = wj__ * bv__;                     \
            u1__ += ta__; u2__ += tb__;                                       \
            a11__ = fmaf(ta__, av__, a11__);                                  \
            a12__ = fmaf(ta__, bv__, a12__);                                  \
            a22__ = fmaf(tb__, bv__, a22__);                                  \
        }                                                                     \
        _Pragma("unroll")                                                     \
        for (int j = (J0_); j <= (J1_); ++j) {                                \
            const int sl__ = ((TM_) + j + 1) % 11;                            \
            float wy__ = gs[10 - j];                                          \
            acc[0][sl__] = fmaf(wy__, u1__,  acc[0][sl__]);                   \
            acc[1][sl__] = fmaf(wy__, u2__,  acc[1][sl__]);                   \
            acc[2][sl__] = fmaf(wy__, a11__, acc[2][sl__]);                   \
            acc[3][sl__] = fmaf(wy__, a22__, acc[3][sl__]);                   \
            acc[4][sl__] = fmaf(wy__, a12__, acc[4][sl__]);                   \
        }                                                                     \
    }                                                                         \
    *(float4*)(WPE_) = h1;          /* stage row T+1 (loaded 3 steps ago) */  \
    if (STORE_) {                                                             \
        const int es__ = ((TM_) + 1) % 11;                                    \
        size_t wo__ = (size_t)(y0 + T__ - 10) * 128;                          \
        _Pragma("unroll")                                                     \
        for (int f = 0; f < 5; ++f) {                                         \
            fb[(size_t)f * S + wo__] = acc[f][es__];                          \
            acc[f][es__] = 0.f;                                               \
        }                                                                     \
    }                                                                         \
    h1 = h2; h2 = Rn__;                                                       \
} while (0)

__global__ __launch_bounds__(128, 2)
void ssimA(const float* __restrict__ img1, const float* __restrict__ img2,
           float* __restrict__ fields) {
    __shared__ __align__(16) float ring[2 * WRING];   // 10 KiB
    float gs[11]; make_g_s(gs);
    const int x = threadIdx.x;                 // 0..127 (output column)
    const int w = x >> 6, l = x & 63;          // wave, lane
    const int b = blockIdx.x;
    const int yc = b & 3, z = (b >> 2) & 127, n = b >> 9;
    const int y0 = yc * 32;
    // lanes 0-31 stage the img1 row (float4 each), lanes 32-63 the img2 row
    const float* src = (l < 32 ? img1 : img2)
                     + (size_t)n * S + (size_t)z * SLICE + 4 * (l & 31);
    float* fb = fields + (size_t)n * 5 * S + (size_t)z * SLICE + x;

    float* wring = ring + w * WRING;           // private per-wave ring
    float* p_rd = wring + (x + 3);             // == [8 + x-5]; +j / +RB+j taps
    float* p_wr = wring + ((l < 32) ? 0 : RB) + 8 + 4 * (l & 31);

    // zero whole ring once: pads stay zero forever (x-boundary = free)
    for (int i = l; i < WRING; i += 64) wring[i] = 0.f;

    float acc[5][11];
#pragma unroll
    for (int f = 0; f < 5; ++f)
#pragma unroll
        for (int s2 = 0; s2 < 11; ++s2) acc[f][s2] = 0.f;

    // prologue: rows for steps 0,1,2; slot0 written, rows 1,2 held in regs
    float4 h1, h2;
    {
        int r0 = min(max(y0 - 5, 0), 127);
        int r1 = min(max(y0 - 4, 0), 127);
        int r2 = min(max(y0 - 3, 0), 127);
        float4 R0 = *(const float4*)(src + (size_t)r0 * 128);
        h1        = *(const float4*)(src + (size_t)r1 * 128);
        h2        = *(const float4*)(src + (size_t)r2 * 128);
        *(float4*)(p_wr) = R0;                 // slot 0
    }

    // head: t = 0..9 (partial y-window, row may be < 0; no stores)
#pragma unroll
    for (int t = 0; t < 10; ++t) {
        STEPA(t, t, 10 - t, 10, false, (y0 + t - 5 >= 0),
              p_rd + (t & 3) * RSLOT, p_wr + ((t + 1) & 3) * RSLOT);
    }
    // steady: t = 10..31 -- branch-free, full window, store every step
    {
        int ro = 2 * RSLOT, wro = 3 * RSLOT;   // slot(10), slot(11)
#pragma unroll 1
        for (int blk = 0; blk < 2; ++blk) {
#pragma unroll
            for (int tt = 0; tt < 11; ++tt) {
                STEPA(10 + blk * 11 + tt, 10 + tt, 0, 10, true, true,
                      p_rd + ro, p_wr + wro);
                ro = wro;
                wro += RSLOT; if (wro == WRING) wro = 0;
            }
        }
    }
    // drain: t = 32..41 (partial y-window, row may be > 127; store always)
#pragma unroll
    for (int t = 32; t < 42; ++t) {
        STEPA(t, t % 11, 0, 41 - t, true, (y0 + t - 5 < 128),
              p_rd + (t & 3) * RSLOT, p_wr + ((t + 1) & 3) * RSLOT);
    }
}

// ---------------- Kernel B: z-conv + map + reduce, walk z ----------------
// grid: 4n * 64y2 * 4zc = 1024 blocks of 256 threads (4 waves).
// Thread owns (x = tid&127, y = 2*y2 + (tid>>7)); walks 32 z outputs.
// Batches reversed (freshest A output first -> L3 hits). Depth-4 prefetch
// (5 floats/step pipeline stage = cheap in regs), 3-phase branch-free loop.
#define STEPB(T_, TM_, J0_, J1_, STORE_, OKC_) do {                           \
    const int T__ = (T_);                                                     \
    int sp__ = T__ + 4; if (sp__ > 41) sp__ = 41;                             \
    size_t off__ = (size_t)min(max(z0 + sp__ - 5, 0), 127) * SLICE;           \
    float N__[5];                                                             \
    _Pragma("unroll")                                                         \
    for (int f = 0; f < 5; ++f) N__[f] = base[(size_t)f * S + off__];         \
    if (OKC_) {                                                               \
        _Pragma("unroll")                                                     \
        for (int j = (J0_); j <= (J1_); ++j) {                                \
            const int sl__ = ((TM_) + j + 1) % 11;                            \
            float wz__ = gs[10 - j];                                          \
            acc[0][sl__] = fmaf(wz__, P0[0], acc[0][sl__]);                   \
            acc[1][sl__] = fmaf(wz__, P0[1], acc[1][sl__]);                   \
            acc[2][sl__] = fmaf(wz__, P0[2], acc[2][sl__]);                   \
            acc[3][sl__] = fmaf(wz__, P0[3], acc[3][sl__]);                   \
            acc[4][sl__] = fmaf(wz__, P0[4], acc[4][sl__]);                   \
        }                                                                     \
    }                                                                         \
    if (STORE_) {                                                             \
        const int es__ = ((TM_) + 1) % 11;                                    \
        float m1__ = acc[0][es__], m2__ = acc[1][es__];                       \
        float p11__ = acc[2][es__], p22__ = acc[3][es__], p12__ = acc[4][es__];\
        float m1s__ = m1__ * m1__, m2s__ = m2__ * m2__, m12__ = m1__ * m2__;  \
        float v1c__ = p11__ - m1s__, v2c__ = p22__ - m2s__, cv__ = p12__ - m12__;\
        float num__ = (2.f * m12__ + C1_) * (2.f * cv__ + C2_);               \
        float den__ = (m1s__ + m2s__ + C1_) * (v1c__ + v2c__ + C2_);          \
        sum += num__ / den__;                                                 \
        _Pragma("unroll")                                                     \
        for (int f = 0; f < 5; ++f) acc[f][es__] = 0.f;                       \
    }                                                                         \
    _Pragma("unroll")                                                         \
    for (int f = 0; f < 5; ++f) {                                             \
        P0[f] = P1[f]; P1[f] = P2[f]; P2[f] = P3[f]; P3[f] = N__[f];          \
    }                                                                         \
} while (0)

__global__ __launch_bounds__(256, 1)
void ssimB(const float* __restrict__ fields, float* __restrict__ partials) {
    float gs[11]; make_g_s(gs);
    const int tid = threadIdx.x;
    const int x = tid & 127, yr = tid >> 7;
    const int b = blockIdx.x;
    const int zc = b & 3, y2 = (b >> 2) & 63;
    const int n = 3 - (b >> 8);                 // reverse batches (L3 hits)
    const int y = y2 * 2 + yr;
    const int z0 = zc * 32;
    const float* base = fields + (size_t)n * 5 * S + (size_t)y * 128 + x;

    float acc[5][11];
#pragma unroll
    for (int f = 0; f < 5; ++f)
#pragma unroll
        for (int s2 = 0; s2 < 11; ++s2) acc[f][s2] = 0.f;

    float sum = 0.f;

    // depth-4 prologue: slices for steps 0..3
    float P0[5], P1[5], P2[5], P3[5];
    {
        size_t o0 = (size_t)min(max(z0 - 5, 0), 127) * SLICE;
        size_t o1 = (size_t)min(max(z0 - 4, 0), 127) * SLICE;
        size_t o2 = (size_t)min(max(z0 - 3, 0), 127) * SLICE;
        size_t o3 = (size_t)min(max(z0 - 2, 0), 127) * SLICE;
#pragma unroll
        for (int f = 0; f < 5; ++f) {
            P0[f] = base[(size_t)f * S + o0];
            P1[f] = base[(size_t)f * S + o1];
            P2[f] = base[(size_t)f * S + o2];
            P3[f] = base[(size_t)f * S + o3];
        }
    }

    // head: t = 0..9
#pragma unroll
    for (int t = 0; t < 10; ++t) {
        STEPB(t, t, 10 - t, 10, false, (z0 + t - 5 >= 0));
    }
    // steady: t = 10..31 -- branch-free
#pragma unroll 1
    for (int blk = 0; blk < 2; ++blk) {
#pragma unroll
        for (int tt = 0; tt < 11; ++tt) {
            STEPB(10 + blk * 11 + tt, 10 + tt, 0, 10, true, true);
        }
    }
    // drain: t = 32..41
#pragma unroll
    for (int t = 32; t < 42; ++t) {
        STEPB(t, t % 11, 0, 41 - t, true, (z0 + t - 5 < 128));
    }

    // 4-wave reduce
#pragma unroll
    for (int o = 32; o > 0; o >>= 1) sum += __shfl_down(sum, o, 64);
    __shared__ float ws4[4];
    if ((tid & 63) == 0) ws4[tid >> 6] = sum;
    __syncthreads();
    if (tid == 0) partials[blockIdx.x] = ws4[0] + ws4[1] + ws4[2] + ws4[3];
}

// ---------------- final reduce ----------------
__global__ void ssim_final(const float* __restrict__ partial, int n,
                           float* __restrict__ out, double inv_count) {
    int tid = threadIdx.x;
    double s = 0.0;
    for (int i = tid; i < n; i += 256) s += (double)partial[i];
#pragma unroll
    for (int o = 32; o > 0; o >>= 1) s += __shfl_down(s, o, 64);
    __shared__ double wsum[4];
    int lane = tid & 63, wid = tid >> 6;
    if (lane == 0) wsum[wid] = s;
    __syncthreads();
    if (tid == 0)
        out[0] = (float)((wsum[0] + wsum[1] + wsum[2] + wsum[3]) * inv_count);
}

extern "C" void kernel_launch(void* const* d_in, const int* in_sizes, int n_in,
                              void* d_out, int out_size, void* d_ws, size_t ws_size,
                              hipStream_t stream) {
    const float* img1 = (const float*)d_in[0];
    const float* img2 = (const float*)d_in[1];
    float* out = (float*)d_out;

    float* fields   = (float*)d_ws;                    // 20*S floats (167.8 MB)
    float* partials = fields + 20 * (size_t)S;         // 1024 floats

    ssimA<<<2048, 128, 0, stream>>>(img1, img2, fields);
    ssimB<<<1024, 256, 0, stream>>>(fields, partials);
    ssim_final<<<1, 256, 0, stream>>>(partials, 1024, out,
                                      1.0 / ((double)S * 4));
}

// Round 7
// 169.034 us; speedup vs baseline: 2.2822x; 1.0828x over previous
//
#include <hip/hip_runtime.h>

// SSIM3D, (4,1,128,128,128) fp32, separable 11-tap Gaussian, scalar mean out.
//
// R13 == R11 semantics, inner x-conv SCALARIZED (no float2 arrays in the
// macro) as a codegen hedge: R11 and its verbatim resubmit R12 both hit
// "container failed twice" (no verdict). Audit x2 found no OOB/alignment/
// ordering fault; the one unusual construct was 84 small float2 arrays in
// the 42x-expanded STEPA -- now replaced by load-and-consume pairs with
// IDENTICAL accumulation order (bit-exact same math).
//
// R11 design (on the proven R10 structure, absmax 0.0 x3):
//  A) x-conv gather 24 ds_read_b32 -> 12 ds_read_b64: aligned window
//     [e, e+11], e=(x-5)&~1, per-parity 12-tap weights w12 (1 zero tap).
//     A was DS-unit-bound: 16 waves x (24*5.8+12) ~ 2420 cyc/CU-step vs
//     VALU 1160 -> reads halved. Ring 4 slots -> 2.
//  B) field-interleaved intermediate [n][z][y][f][x]: A's 5 stores / B's 5
//     loads per step in one 2560 B cluster instead of 5 streams 8.4MB apart.
// Launch bounds at empirically spill-free values (effective VGPR cap =
// 512/(arg2 * waves_per_block)): A(128,2)=128, B(256,1)=128.
// Invariant: ssimA WRITE_SIZE ~= 169984 KB (no scratch).

#define SLICE (128*128)        // 16384
#define S  (128*SLICE)         // 2097152 per field per batch
#define ZROW 640               // 5 fields * 128 x  (interleaved row)
#define ZSL  81920             // 128 y * ZROW      (interleaved slice)
#define C1_ 0.0001f
#define C2_ 0.0009f

__device__ __forceinline__ void make_g_s(float* gs) {
    float g[11]; float s = 0.f;
#pragma unroll
    for (int i = 0; i < 11; ++i) {
        float d = (float)(i - 5);
        g[i] = __expf(-d * d / 4.5f);
        s += g[i];
    }
    float inv = 1.f / s;
#pragma unroll
    for (int i = 0; i < 11; ++i)
        gs[i] = __int_as_float(__builtin_amdgcn_readfirstlane(
                    __float_as_int(g[i] * inv)));
}

// ---------------- Kernel A: x-conv + y-conv, walk y ----------------
// grid: 4n * 128z * 4yc = 2048 blocks of 128 threads (2 independent waves).
// Thread owns x = tid; walks 32 y outputs (42 input rows).
// Per-wave LDS ring: 2 slots x (img1 row | img2 row), rows padded to 160
// floats (data at dwords [8..135], zeros outside): taps are maskless.
#define RB    160              // dwords per padded row
#define RSLOT (2*RB)           // 320 dwords per ring slot
#define WRING (2*RSLOT)        // 640 dwords per wave ring (2 slots)

// One pipeline step. T_ runtime step index, TM_ compile-time (== T_ mod 11),
// J0_/J1_ compile-time y-tap range, RPE_/WPE_ read/write slot pointers.
// x-conv: 6 aligned float2 pairs per row, loaded and consumed immediately
// (same accumulation order as the array form -- bit-identical result).
#define STEPA(T_, TM_, J0_, J1_, STORE_, OKC_, RPE_, WPE_) do {               \
    const int T__ = (T_);                                                     \
    int sp__ = T__ + 3; if (sp__ > 41) sp__ = 41;                             \
    int rowc__ = min(max(y0 + sp__ - 5, 0), 127);                             \
    float4 Rn__ = *(const float4*)(src + (size_t)rowc__ * 128);               \
    if (OKC_) {                                                               \
        const float* rp__ = (RPE_);                                           \
        float u1__ = 0.f, u2__ = 0.f, a11__ = 0.f, a22__ = 0.f, a12__ = 0.f;  \
        _Pragma("unroll")                                                     \
        for (int j = 0; j < 6; ++j) {                                         \
            float2 va__ = *(const float2*)(rp__ + 2 * j);                     \
            float2 vb__ = *(const float2*)(rp__ + RB + 2 * j);                \
            {                                                                 \
                float wj__ = w12[2 * j];                                      \
                float ta__ = wj__ * va__.x, tb__ = wj__ * vb__.x;             \
                u1__ += ta__; u2__ += tb__;                                   \
                a11__ = fmaf(ta__, va__.x, a11__);                            \
                a12__ = fmaf(ta__, vb__.x, a12__);                            \
                a22__ = fmaf(tb__, vb__.x, a22__);                            \
            }                                                                 \
            {                                                                 \
                float wj__ = w12[2 * j + 1];                                  \
                float ta__ = wj__ * va__.y, tb__ = wj__ * vb__.y;             \
                u1__ += ta__; u2__ += tb__;                                   \
                a11__ = fmaf(ta__, va__.y, a11__);                            \
                a12__ = fmaf(ta__, vb__.y, a12__);                            \
                a22__ = fmaf(tb__, vb__.y, a22__);                            \
            }                                                                 \
        }                                                                     \
        _Pragma("unroll")                                                     \
        for (int j = (J0_); j <= (J1_); ++j) {                                \
            const int sl__ = ((TM_) + j + 1) % 11;                            \
            float wy__ = gs[10 - j];                                          \
            acc[0][sl__] = fmaf(wy__, u1__,  acc[0][sl__]);                   \
            acc[1][sl__] = fmaf(wy__, u2__,  acc[1][sl__]);                   \
            acc[2][sl__] = fmaf(wy__, a11__, acc[2][sl__]);                   \
            acc[3][sl__] = fmaf(wy__, a22__, acc[3][sl__]);                   \
            acc[4][sl__] = fmaf(wy__, a12__, acc[4][sl__]);                   \
        }                                                                     \
    }                                                                         \
    *(float4*)(WPE_) = h1;          /* stage row T+1 (loaded 3 steps ago) */  \
    if (STORE_) {                                                             \
        size_t wo__ = (size_t)(y0 + T__ - 10) * ZROW;                         \
        const int es__ = ((TM_) + 1) % 11;                                    \
        _Pragma("unroll")                                                     \
        for (int f = 0; f < 5; ++f) {                                         \
            fb[wo__ + f * 128] = acc[f][es__];                                \
            acc[f][es__] = 0.f;                                               \
        }                                                                     \
    }                                                                         \
    h1 = h2; h2 = Rn__;                                                       \
} while (0)

__global__ __launch_bounds__(128, 2)
void ssimA(const float* __restrict__ img1, const float* __restrict__ img2,
           float* __restrict__ fields) {
    __shared__ __align__(16) float ring[2 * WRING];   // 5 KiB
    float gs[11]; make_g_s(gs);
    const int x = threadIdx.x;                 // 0..127 (output column)
    const int w = x >> 6, l = x & 63;          // wave, lane
    const int b = blockIdx.x;
    const int yc = b & 3, z = (b >> 2) & 127, n = b >> 9;
    const int y0 = yc * 32;
    // lanes 0-31 stage the img1 row (float4 each), lanes 32-63 the img2 row
    const float* src = (l < 32 ? img1 : img2)
                     + (size_t)n * S + (size_t)z * SLICE + 4 * (l & 31);
    float* fb = fields + (size_t)(n * 128 + z) * ZSL + x;

    // per-parity 12-tap weights over the aligned window [e, e+11],
    // e = (x-5)&~1, p = (x-5)&1; tap k has weight g[k-p] (0 outside 0..10).
    const int p = (x - 5) & 1;
    const int e = (x - 5) - p;                 // even, in [-6, 122]
    float w12[12];
#pragma unroll
    for (int k = 0; k < 12; ++k) {
        float we = (k <= 10) ? gs[k] : 0.f;            // p == 0
        float wo = (k >= 1) ? gs[k - 1] : 0.f;         // p == 1
        w12[k] = p ? wo : we;
    }

    float* wring = ring + w * WRING;           // private per-wave ring
    float* p_rd = wring + (8 + e);             // aligned window base (8B)
    float* p_wr = wring + ((l < 32) ? 0 : RB) + 8 + 4 * (l & 31);

    // zero whole ring once: pads stay zero forever (x-boundary = free)
    for (int i = l; i < WRING; i += 64) wring[i] = 0.f;

    float acc[5][11];
#pragma unroll
    for (int f = 0; f < 5; ++f)
#pragma unroll
        for (int s2 = 0; s2 < 11; ++s2) acc[f][s2] = 0.f;

    // prologue: rows for steps 0,1,2; slot0 written, rows 1,2 held in regs
    float4 h1, h2;
    {
        int r0 = min(max(y0 - 5, 0), 127);
        int r1 = min(max(y0 - 4, 0), 127);
        int r2 = min(max(y0 - 3, 0), 127);
        float4 R0 = *(const float4*)(src + (size_t)r0 * 128);
        h1        = *(const float4*)(src + (size_t)r1 * 128);
        h2        = *(const float4*)(src + (size_t)r2 * 128);
        *(float4*)(p_wr) = R0;                 // slot 0
    }

    // head: t = 0..9 (partial y-window, row may be < 0; no stores)
#pragma unroll
    for (int t = 0; t < 10; ++t) {
        STEPA(t, t, 10 - t, 10, false, (y0 + t - 5 >= 0),
              p_rd + (t & 1) * RSLOT, p_wr + ((t + 1) & 1) * RSLOT);
    }
    // steady: t = 10..31 -- branch-free, full window, store every step
    {
        int ro = 0, wro = RSLOT;               // slot(10)=0, slot(11)=1
#pragma unroll 1
        for (int blk = 0; blk < 2; ++blk) {
#pragma unroll
            for (int tt = 0; tt < 11; ++tt) {
                STEPA(10 + blk * 11 + tt, 10 + tt, 0, 10, true, true,
                      p_rd + ro, p_wr + wro);
                ro ^= RSLOT; wro ^= RSLOT;
            }
        }
    }
    // drain: t = 32..41 (partial y-window, row may be > 127; store always)
#pragma unroll
    for (int t = 32; t < 42; ++t) {
        STEPA(t, t % 11, 0, 41 - t, true, (y0 + t - 5 < 128),
              p_rd + (t & 1) * RSLOT, p_wr + ((t + 1) & 1) * RSLOT);
    }
}

// ---------------- Kernel B: z-conv + map + reduce, walk z ----------------
// grid: 4n * 64y2 * 4zc = 1024 blocks of 256 threads (4 waves).
// Thread owns (x = tid&127, y = 2*y2 + (tid>>7)); walks 32 z outputs.
// Batches reversed (freshest A output first -> L3 hits). Depth-4 prefetch;
// interleaved layout: the 5 per-step loads sit within one 2560 B cluster.
#define STEPB(T_, TM_, J0_, J1_, STORE_, OKC_) do {                           \
    const int T__ = (T_);                                                     \
    int sp__ = T__ + 4; if (sp__ > 41) sp__ = 41;                             \
    size_t off__ = (size_t)min(max(z0 + sp__ - 5, 0), 127) * ZSL;             \
    float N0__ = base[off__];                                                 \
    float N1__ = base[off__ + 128];                                           \
    float N2__ = base[off__ + 256];                                           \
    float N3__ = base[off__ + 384];                                           \
    float N4__ = base[off__ + 512];                                           \
    if (OKC_) {                                                               \
        _Pragma("unroll")                                                     \
        for (int j = (J0_); j <= (J1_); ++j) {                                \
            const int sl__ = ((TM_) + j + 1) % 11;                            \
            float wz__ = gs[10 - j];                                          \
            acc[0][sl__] = fmaf(wz__, P0[0], acc[0][sl__]);                   \
            acc[1][sl__] = fmaf(wz__, P0[1], acc[1][sl__]);                   \
            acc[2][sl__] = fmaf(wz__, P0[2], acc[2][sl__]);                   \
            acc[3][sl__] = fmaf(wz__, P0[3], acc[3][sl__]);                   \
            acc[4][sl__] = fmaf(wz__, P0[4], acc[4][sl__]);                   \
        }                                                                     \
    }                                                                         \
    if (STORE_) {                                                             \
        const int es__ = ((TM_) + 1) % 11;                                    \
        float m1__ = acc[0][es__], m2__ = acc[1][es__];                       \
        float p11__ = acc[2][es__], p22__ = acc[3][es__], p12__ = acc[4][es__];\
        float m1s__ = m1__ * m1__, m2s__ = m2__ * m2__, m12__ = m1__ * m2__;  \
        float v1c__ = p11__ - m1s__, v2c__ = p22__ - m2s__, cv__ = p12__ - m12__;\
        float num__ = (2.f * m12__ + C1_) * (2.f * cv__ + C2_);               \
        float den__ = (m1s__ + m2s__ + C1_) * (v1c__ + v2c__ + C2_);          \
        sum += num__ / den__;                                                 \
        _Pragma("unroll")                                                     \
        for (int f = 0; f < 5; ++f) acc[f][es__] = 0.f;                       \
    }                                                                         \
    _Pragma("unroll")                                                         \
    for (int f = 0; f < 5; ++f) { P0[f] = P1[f]; P1[f] = P2[f]; P2[f] = P3[f]; } \
    P3[0] = N0__; P3[1] = N1__; P3[2] = N2__; P3[3] = N3__; P3[4] = N4__;     \
} while (0)

__global__ __launch_bounds__(256, 1)
void ssimB(const float* __restrict__ fields, float* __restrict__ partials) {
    float gs[11]; make_g_s(gs);
    const int tid = threadIdx.x;
    const int x = tid & 127, yr = tid >> 7;
    const int b = blockIdx.x;
    const int zc = b & 3, y2 = (b >> 2) & 63;
    const int n = 3 - (b >> 8);                 // reverse batches (L3 hits)
    const int y = y2 * 2 + yr;
    const int z0 = zc * 32;
    const float* base = fields + (size_t)n * 128 * ZSL + (size_t)y * ZROW + x;

    float acc[5][11];
#pragma unroll
    for (int f = 0; f < 5; ++f)
#pragma unroll
        for (int s2 = 0; s2 < 11; ++s2) acc[f][s2] = 0.f;

    float sum = 0.f;

    // depth-4 prologue: slices for steps 0..3
    float P0[5], P1[5], P2[5], P3[5];
    {
        size_t o0 = (size_t)min(max(z0 - 5, 0), 127) * ZSL;
        size_t o1 = (size_t)min(max(z0 - 4, 0), 127) * ZSL;
        size_t o2 = (size_t)min(max(z0 - 3, 0), 127) * ZSL;
        size_t o3 = (size_t)min(max(z0 - 2, 0), 127) * ZSL;
#pragma unroll
        for (int f = 0; f < 5; ++f) {
            P0[f] = base[o0 + f * 128];
            P1[f] = base[o1 + f * 128];
            P2[f] = base[o2 + f * 128];
            P3[f] = base[o3 + f * 128];
        }
    }

    // head: t = 0..9
#pragma unroll
    for (int t = 0; t < 10; ++t) {
        STEPB(t, t, 10 - t, 10, false, (z0 + t - 5 >= 0));
    }
    // steady: t = 10..31 -- branch-free
#pragma unroll 1
    for (int blk = 0; blk < 2; ++blk) {
#pragma unroll
        for (int tt = 0; tt < 11; ++tt) {
            STEPB(10 + blk * 11 + tt, 10 + tt, 0, 10, true, true);
        }
    }
    // drain: t = 32..41
#pragma unroll
    for (int t = 32; t < 42; ++t) {
        STEPB(t, t % 11, 0, 41 - t, true, (z0 + t - 5 < 128));
    }

    // 4-wave reduce
#pragma unroll
    for (int o = 32; o > 0; o >>= 1) sum += __shfl_down(sum, o, 64);
    __shared__ float ws4[4];
    if ((tid & 63) == 0) ws4[tid >> 6] = sum;
    __syncthreads();
    if (tid == 0) partials[blockIdx.x] = ws4[0] + ws4[1] + ws4[2] + ws4[3];
}

// ---------------- final reduce ----------------
__global__ void ssim_final(const float* __restrict__ partial, int n,
                           float* __restrict__ out, double inv_count) {
    int tid = threadIdx.x;
    double s = 0.0;
    for (int i = tid; i < n; i += 256) s += (double)partial[i];
#pragma unroll
    for (int o = 32; o > 0; o >>= 1) s += __shfl_down(s, o, 64);
    __shared__ double wsum[4];
    int lane = tid & 63, wid = tid >> 6;
    if (lane == 0) wsum[wid] = s;
    __syncthreads();
    if (tid == 0)
        out[0] = (float)((wsum[0] + wsum[1] + wsum[2] + wsum[3]) * inv_count);
}

extern "C" void kernel_launch(void* const* d_in, const int* in_sizes, int n_in,
                              void* d_out, int out_size, void* d_ws, size_t ws_size,
                              hipStream_t stream) {
    const float* img1 = (const float*)d_in[0];
    const float* img2 = (const float*)d_in[1];
    float* out = (float*)d_out;

    float* fields   = (float*)d_ws;                    // 20*S floats (167.8 MB)
    float* partials = fields + 20 * (size_t)S;         // 1024 floats

    ssimA<<<2048, 128, 0, stream>>>(img1, img2, fields);
    ssimB<<<1024, 256, 0, stream>>>(fields, partials);
    ssim_final<<<1, 256, 0, stream>>>(partials, 1024, out,
                                      1.0 / ((double)S * 4));
}